// Round 12
// baseline (4545.597 us; speedup 1.0000x reference)
//
#include <hip/hip_runtime.h>

#define T_STEPS 512
#define BATCH   128
#define DIN     512
#define HDIM    512
#define THREEH  1536
#define LDK     520    // padded K stride in halves
#define LDG     49
#define SPIN_MAX (1 << 16)   // bounded spin: wedge -> wrong answer, never hang
#define HS_SPIN  512
// v1 fallback geometry (small-ws)
#define THREADS 256
#define NGROUP  4
#define NSLICE  32
#define BC      32
#define HC      16
#define NC      48
#define CNT_STRIDE 16
#define EX_DWORDS (NSLICE * BATCH * HC / 2)
// v8 geometry: 8 cohorts x 16 rows; 32 slices x 16 cols; 320 threads (5 waves)
#define THREADS8 320
#define RW 16
#define EXSLOT 131072        // 8g x 16r x 512c x 2B
// ws layout (first 8KB memset each launch)
#define FLAGS_OFF  0         // 8 cohorts x 128 wave-flags x 4B = 4KB
#define GBAR_OFF   4096      // 8 counters x 64B
#define NONCE_OFF  4608
#define DEC_OFF    4736
#define VD_OFF     5120      // 256 uints
#define HS_OFF     6144      // 256 uints
#define MEMSET_BYTES 8192
#define EX_OFF     8192      // 2 x 128KB exchange
#define GI_OFF     (1u<<20)
#define GI_BYTES   201326592ULL

typedef _Float16 half8 __attribute__((ext_vector_type(8)));
typedef _Float16 half4v __attribute__((ext_vector_type(4)));
typedef float    f32x4 __attribute__((ext_vector_type(4)));
typedef unsigned int uint4v __attribute__((ext_vector_type(4)));

__global__ void sniff_kernel(const unsigned int* __restrict__ w,
                             unsigned int* __restrict__ dec) {
  unsigned int local = 0;
  for (int i = threadIdx.x; i < (T_STEPS * BATCH) / 4; i += 256) {
    if (w[i] > 1u) local = 1u;
  }
  if (local) atomicOr(dec, 1u);
}

// ======================= v1 fallback (round-4, proven; small-ws only) =======================
__device__ __forceinline__ void run_gemm(const _Float16* __restrict__ sAa,
                                         const _Float16* __restrict__ sW,
                                         float* __restrict__ sAcc,
                                         int wid, int lane) {
  const int fr = lane & 15;
  const int kb = (lane >> 4) * 8;
  for (int tile = wid; tile < 6; tile += 4) {
    int mi = tile / 3, ni = tile - mi * 3;
    const _Float16* ap = sAa + (mi * 16 + fr) * LDK + kb;
    const _Float16* bp = sW  + (ni * 16 + fr) * LDK + kb;
    f32x4 acc = {0.f, 0.f, 0.f, 0.f};
#pragma unroll
    for (int kk = 0; kk < DIN / 32; ++kk)
      acc = __builtin_amdgcn_mfma_f32_16x16x32_f16(
          *(const half8*)(ap + kk * 32),
          *(const half8*)(bp + kk * 32), acc, 0, 0, 0);
    int crow = mi * 16 + (lane >> 4) * 4;
    int ccol = ni * 16 + fr;
#pragma unroll
    for (int j = 0; j < 4; ++j) sAcc[(crow + j) * LDG + ccol] = acc[j];
  }
}

__global__ __launch_bounds__(THREADS, 1)
void gru_kernel_v1(const float* __restrict__ carry,
                   const float* __restrict__ ins,
                   const void*  __restrict__ resets_raw,
                   const float* __restrict__ Wi,
                   const float* __restrict__ Wh,
                   const float* __restrict__ bh,
                   float* __restrict__ out,
                   unsigned int* __restrict__ cnt,
                   unsigned int* __restrict__ ex0,
                   unsigned int* __restrict__ ex1,
                   const unsigned int* __restrict__ dec)
{
  __shared__ alignas(16) _Float16 sWi[NC * LDK];
  __shared__ alignas(16) _Float16 sWh[NC * LDK];
  __shared__ alignas(16) _Float16 sA [BC * LDK];
  __shared__ float sGi[BC * LDG];
  __shared__ float sGh[BC * LDG];
  __shared__ float sBh[NC];
  __shared__ int   sRst[BC];

  const int tid  = threadIdx.x;
  const int bid  = blockIdx.x;
  const int g    = bid & (NGROUP - 1);
  const int p    = bid >> 2;
  const int row0 = g * BC;
  const int col0 = p * HC;

  float* carryOut = out;
  float* ys = out + BATCH * HDIM;

  const unsigned int isBool = *dec;
  const unsigned char* r8  = (const unsigned char*)resets_raw;
  const int*           r32 = (const int*)resets_raw;

  unsigned int* ex[2] = { ex0, ex1 };
  unsigned int* myCnt = cnt + g * CNT_STRIDE;

  for (int idx = tid; idx < DIN * NC; idx += THREADS) {
    int k  = idx / NC;
    int ci = idx - k * NC;
    int gcol = (ci >> 4) * HDIM + col0 + (ci & 15);
    sWi[ci * LDK + k] = (_Float16)Wi[k * THREEH + gcol];
    sWh[ci * LDK + k] = (_Float16)Wh[k * THREEH + gcol];
  }
  if (tid < NC) {
    int gcol = (tid >> 4) * HDIM + col0 + (tid & 15);
    sBh[tid] = bh[gcol];
  }

  float hreg[2];
  {
    int idx = tid * 2;
    int b0 = idx >> 4, c0 = idx & 15;
    hreg[0] = carry[(size_t)(row0 + b0) * HDIM + col0 + c0];
    hreg[1] = carry[(size_t)(row0 + b0) * HDIM + col0 + c0 + 1];
  }

  const int wid  = tid >> 6;
  const int lane = tid & 63;

  auto stageRst = [&](int t) {
    if (tid < BC) {
      int off = t * BATCH + row0 + tid;
      sRst[tid] = isBool ? (int)r8[off] : r32[off];
    }
  };
  auto stageX = [&](int t) {
    const float4* src = (const float4*)(ins + (size_t)(t * BATCH + row0) * DIN);
    for (int i = tid; i < BC * (DIN / 4); i += THREADS) {
      int r = i >> 7, c4 = i & 127;
      float4 v = src[(size_t)r * 128 + c4];
      half4v hv = {(_Float16)v.x, (_Float16)v.y, (_Float16)v.z, (_Float16)v.w};
      *(half4v*)&sA[r * LDK + c4 * 4] = hv;
    }
  };

  stageRst(0);
  stageX(0);
  __syncthreads();
  run_gemm(sA, sWi, sGi, wid, lane);
  __syncthreads();
  {
    const float4* src = (const float4*)(carry + (size_t)row0 * HDIM);
    for (int i = tid; i < BC * (HDIM / 4); i += THREADS) {
      int r = i >> 7, c4 = i & 127;
      float4 v = src[(size_t)r * 128 + c4];
      float m = sRst[r] ? 0.f : 1.f;
      half4v hv = {(_Float16)(v.x*m), (_Float16)(v.y*m),
                   (_Float16)(v.z*m), (_Float16)(v.w*m)};
      *(half4v*)&sA[r * LDK + c4 * 4] = hv;
    }
  }
  __syncthreads();

  for (int t = 0; t < T_STEPS; ++t) {
    if (t > 0) {
      {
        const unsigned int target = 32u * (unsigned)t;
        unsigned int fv;
        for (int it = 0; it < SPIN_MAX; ++it) {
          asm volatile("global_load_dword %0, %1, off sc0 sc1\n\t"
                       "s_waitcnt vmcnt(0)"
                       : "=v"(fv) : "v"(myCnt) : "memory");
          if (fv >= target) break;
          __builtin_amdgcn_s_sleep(1);
        }
      }
      {
        const unsigned int* exsrc = ex[(t - 1) & 1];
        uint4v vv[8];
#pragma unroll
        for (int j = 0; j < 8; ++j) {
          int i = tid + THREADS * j;
          int p_ = i >> 6, b_ = (i >> 1) & 31, hw = (i & 1) << 2;
          const unsigned int* sp = exsrc + p_ * 1024 + (row0 + b_) * 8 + hw;
          asm volatile("global_load_dwordx4 %0, %1, off sc0 sc1"
                       : "=&v"(vv[j]) : "v"(sp) : "memory");
        }
        asm volatile("s_waitcnt vmcnt(0)" ::: "memory");
        __builtin_amdgcn_sched_barrier(0);
#pragma unroll
        for (int j = 0; j < 8; ++j) {
          int i = tid + THREADS * j;
          int p_ = i >> 6, b_ = (i >> 1) & 31, hw = (i & 1) << 3;
          half8 hv = *reinterpret_cast<half8*>(&vv[j]);
          half8 z = {(_Float16)0, (_Float16)0, (_Float16)0, (_Float16)0,
                     (_Float16)0, (_Float16)0, (_Float16)0, (_Float16)0};
          hv = sRst[b_] ? z : hv;
          *(half8*)&sA[b_ * LDK + p_ * 16 + hw] = hv;
        }
      }
      __syncthreads();
    }

    run_gemm(sA, sWh, sGh, wid, lane);
    __syncthreads();

    {
#pragma unroll
      for (int e = 0; e < 2; ++e) {
        int idx = tid * 2 + e;
        int b = idx >> 4, cj = idx & 15;
        float gir = sGi[b * LDG + cj];
        float giz = sGi[b * LDG + 16 + cj];
        float gin = sGi[b * LDG + 32 + cj];
        float ghr = sGh[b * LDG + cj]      + sBh[cj];
        float ghz = sGh[b * LDG + 16 + cj] + sBh[16 + cj];
        float ghn = sGh[b * LDG + 32 + cj] + sBh[32 + cj];
        float r = 1.f / (1.f + __expf(-(gir + ghr)));
        float z = 1.f / (1.f + __expf(-(giz + ghz)));
        float n = tanhf(gin + r * ghn);
        float hp = sRst[b] ? 0.f : hreg[e];
        hreg[e] = (1.f - z) * n + z * hp;
      }
      union { _Float16 h[2]; unsigned int u; } pk;
      pk.h[0] = (_Float16)hreg[0];
      pk.h[1] = (_Float16)hreg[1];
      unsigned int* dst = ex[t & 1] + p * 1024 + (row0 + (tid >> 3)) * 8 + (tid & 7);
      asm volatile("global_store_dword %0, %1, off sc0 sc1"
                   :: "v"(dst), "v"(pk.u) : "memory");
      int b0 = (tid * 2) >> 4, c0 = (tid * 2) & 15;
      float2 yv = make_float2(hreg[0], hreg[1]);
      *(float2*)&ys[((size_t)t * BATCH + row0 + b0) * HDIM + col0 + c0] = yv;
      if (t == T_STEPS - 1)
        *(float2*)&carryOut[(size_t)(row0 + b0) * HDIM + col0 + c0] = yv;
    }
    asm volatile("s_waitcnt vmcnt(0)" ::: "memory");
    __syncthreads();
    if (tid == 0) atomicAdd(myCnt, 1u);

    if (t < T_STEPS - 1) {
      stageRst(t + 1);
      stageX(t + 1);
      __syncthreads();
      run_gemm(sA, sWi, sGi, wid, lane);
      __syncthreads();
    }
  }
}

// ============ gi prepass (round-7, proven): register-pipelined staging ============
__global__ __launch_bounds__(256, 1)
void gi_prepass2(const float* __restrict__ ins,
                 const float* __restrict__ Wi,
                 _Float16* __restrict__ gis)
{
  __shared__ alignas(16) _Float16 sWiT[48 * LDK];
  __shared__ alignas(16) _Float16 sX[32 * LDK];

  const int tid = threadIdx.x;
  const int bid = blockIdx.x;
  const int n   = bid >> 3;
  const int mg  = bid & 7;
  const int wid = tid >> 6;
  const int lane = tid & 63;
  const int fr = lane & 15;
  const int kb = (lane >> 4) * 8;

  for (int idx = tid; idx < 48 * DIN; idx += 256) {
    int ci = idx % 48, k = idx / 48;
    int gcol = (ci >> 4) * HDIM + n * 16 + (ci & 15);
    sWiT[ci * LDK + k] = (_Float16)Wi[(size_t)k * THREEH + gcol];
  }

  float4 va[16];
  auto LOADS = [&](int ch) {
    const float4* src = (const float4*)(ins + (size_t)(mg * 8192 + ch * 32) * DIN);
#pragma unroll
    for (int j = 0; j < 16; ++j) va[j] = src[tid + 256 * j];
  };
  auto WRITE = [&]() {
#pragma unroll
    for (int j = 0; j < 16; ++j) {
      int i = tid + 256 * j;
      int r = i >> 7, c4 = i & 127;
      float4 v = va[j];
      half4v hv = {(_Float16)v.x, (_Float16)v.y, (_Float16)v.z, (_Float16)v.w};
      *(half4v*)&sX[r * LDK + c4 * 4] = hv;
    }
  };

  LOADS(0);
  for (int ch = 0; ch < 256; ++ch) {
    WRITE();
    __syncthreads();
    if (ch + 1 < 256) LOADS(ch + 1);

    const int m0 = mg * 8192 + ch * 32;
    const int tt = m0 >> 7;
    const int bb0 = m0 & 127;
    for (int tile = wid; tile < 6; tile += 4) {
      int mi = tile / 3, ni = tile - mi * 3;
      const _Float16* ap = sX   + (mi * 16 + fr) * LDK + kb;
      const _Float16* bp = sWiT + (ni * 16 + fr) * LDK + kb;
      f32x4 acc = {0.f, 0.f, 0.f, 0.f};
#pragma unroll
      for (int kk = 0; kk < DIN / 32; ++kk)
        acc = __builtin_amdgcn_mfma_f32_16x16x32_f16(
            *(const half8*)(ap + kk * 32),
            *(const half8*)(bp + kk * 32), acc, 0, 0, 0);
      int gr = mi * 16 + ((lane >> 4) << 2);
      int col = n * 16 + fr;
      size_t base = ((size_t)(tt * 3 + ni) * BATCH) * HDIM + col;
#pragma unroll
      for (int j = 0; j < 4; ++j)
        gis[base + (size_t)(bb0 + gr + j) * HDIM] = (_Float16)acc[j];
    }
    __syncthreads();
  }
}

// ============ v8: v4-fast protocol, 5 waves, gi-pipe wave, 2 barriers/step ============
__device__ __forceinline__ void gridbar8(unsigned int* ctr, int tid) {
  __syncthreads();
  if (tid == 0) {
    atomicAdd(ctr, 1u);
    unsigned int v;
    for (int it = 0; it < SPIN_MAX; ++it) {
      asm volatile("global_load_dword %0, %1, off sc0 sc1\n\t"
                   "s_waitcnt vmcnt(0)" : "=v"(v) : "v"(ctr) : "memory");
      if (v >= 256u) break;
      __builtin_amdgcn_s_sleep(1);
    }
  }
  __syncthreads();
}

__global__ __launch_bounds__(THREADS8, 1)
void gru_kernel_v8(const float* __restrict__ carry,
                   const void*  __restrict__ resets_raw,
                   const float* __restrict__ Wh,
                   const float* __restrict__ bh,
                   float* __restrict__ out,
                   unsigned int* __restrict__ wsb,
                   const _Float16* __restrict__ gis,
                   const unsigned int* __restrict__ dec)
{
  __shared__ alignas(16) _Float16 sWh[NC * LDK];      // 49,920
  __shared__ alignas(16) _Float16 sA [RW * LDK];      // 16,640
  __shared__ alignas(16) _Float16 sGi2[2 * 768];      // 3,072 (gi double buffer)
  __shared__ float sGh[RW * LDG];                     // 3,136
  __shared__ float sBh[NC];
  __shared__ unsigned short sRstB[T_STEPS];           // 1,024 bitmask/step
  __shared__ int   sFast;
  __shared__ unsigned int sNonce;

  const int tid  = threadIdx.x;
  const int bid  = blockIdx.x;
  const int g    = bid & 7;        // cohort (presumed XCD)
  const int p    = bid >> 3;       // col slice 0..31
  const int row0 = g * RW;
  const int col0 = p * HC;

  unsigned int* flags    = wsb + (FLAGS_OFF / 4);   // [g][128] = p*4+wid
  unsigned int* gbars    = wsb + (GBAR_OFF / 4);
  unsigned int* nonceArr = wsb + (NONCE_OFF / 4);
  unsigned int* vd       = wsb + (VD_OFF / 4);
  unsigned int* hs       = wsb + (HS_OFF / 4);
  char*         exb      = (char*)wsb + EX_OFF;

  float* carryOut = out;
  float* ys = out + BATCH * HDIM;

  const unsigned int isBool = *dec;
  const unsigned char* r8  = (const unsigned char*)resets_raw;
  const int*           r32 = (const int*)resets_raw;
  const unsigned short* gisu = (const unsigned short*)gis;

  const int wid  = tid >> 6;       // 0..4
  const int lane = tid & 63;
  const int fr   = lane & 15;
  const int kb   = (lane >> 4) * 8;
  const int gb   = tid >> 4;       // gates row (tid<256)
  const int gc   = tid & 15;       // gates col

  // ---- weights / bias / rst bitmask / state ----
  for (int idx = tid; idx < DIN * NC; idx += THREADS8) {
    int k  = idx / NC;
    int ci = idx - k * NC;
    int gcol = (ci >> 4) * HDIM + col0 + (ci & 15);
    sWh[ci * LDK + k] = (_Float16)Wh[(size_t)k * THREEH + gcol];
  }
  if (tid < NC) {
    int gcol = (tid >> 4) * HDIM + col0 + (tid & 15);
    sBh[tid] = bh[gcol];
  }
  for (int tt = tid; tt < T_STEPS; tt += THREADS8) {
    unsigned int m = 0;
#pragma unroll
    for (int r = 0; r < RW; ++r) {
      int off = tt * BATCH + row0 + r;
      int v = isBool ? (int)r8[off] : r32[off];
      m |= (v ? 1u : 0u) << r;
    }
    sRstB[tt] = (unsigned short)m;
  }
  float hreg = 0.f;
  if (tid < 256) hreg = carry[(size_t)(row0 + gb) * HDIM + col0 + gc];

  // ---- nonce handshake (v7 verbatim, proven): selects sc0 vs sc0sc1 ----
  if (p == 0 && tid == 0) {
    unsigned long long tv = __builtin_amdgcn_s_memrealtime();
    unsigned int nv = (unsigned int)(tv ^ (tv >> 32));
    if (nv == 0) nv = 0x5A5A5A5Au;
    asm volatile("global_store_dword %0, %1, off sc0 sc1\n\t"
                 "s_waitcnt vmcnt(0)" :: "v"(nonceArr + g), "v"(nv) : "memory");
  }
  gridbar8(gbars + 0 * 16, tid);
  if (tid == 0) {
    unsigned int nv;
    asm volatile("global_load_dword %0, %1, off sc0 sc1\n\t"
                 "s_waitcnt vmcnt(0)" : "=v"(nv) : "v"(nonceArr + g) : "memory");
    sNonce = nv;
  }
  __syncthreads();
  const unsigned int nonce = sNonce;

  bool okAll = true;
  for (int r = 0; r < 2; ++r) {
    if (tid == 0) {
      unsigned int tok = nonce ^ ((unsigned)p << 8) ^ ((unsigned)(r + 1) << 20);
      asm volatile("global_store_dword %0, %1, off sc0\n\t"
                   "s_waitcnt vmcnt(0)" :: "v"(hs + bid), "v"(tok) : "memory");
    }
    __syncthreads();
    if (tid < 32) {
      unsigned int expv = nonce ^ ((unsigned)tid << 8) ^ ((unsigned)(r + 1) << 20);
      const unsigned int* hp = hs + (g + 8 * tid);
      bool got = false;
      for (int it = 0; it < HS_SPIN && !got; ++it) {
        unsigned int v;
        asm volatile("global_load_dword %0, %1, off sc0\n\t"
                     "s_waitcnt vmcnt(0)" : "=v"(v) : "v"(hp) : "memory");
        got = (v == expv);
      }
      okAll = okAll && got;
    }
    gridbar8(gbars + (1 + r) * 16, tid);
  }
  {
    bool wgok = __all((tid < 32) ? okAll : true);
    if (tid == 0) {
      unsigned int vv = wgok ? 1u : 0u;
      asm volatile("global_store_dword %0, %1, off sc0 sc1\n\t"
                   "s_waitcnt vmcnt(0)" :: "v"(vd + bid), "v"(vv) : "memory");
    }
    gridbar8(gbars + 3 * 16, tid);
    bool fin = true;
    if (tid < 32) {
      unsigned int v;
      asm volatile("global_load_dword %0, %1, off sc0 sc1\n\t"
                   "s_waitcnt vmcnt(0)" : "=v"(v) : "v"(vd + (g + 8 * tid)) : "memory");
      fin = (v == 1u);
    }
    bool unan = __all((tid < 32) ? fin : true);
    if (tid == 0) sFast = unan ? 1 : 0;
    __syncthreads();
  }
  const int fast = sFast;

  // ---- prologue: gi(0) -> sGi2 slot 0 (sync); wave4 issues gi(1) ----
  if (tid < 256) {
    size_t base = ((size_t)0 * BATCH + row0 + gb) * HDIM + col0 + gc;
    union { unsigned short u; _Float16 h; } c;
    c.u = gisu[base];                              sGi2[0 * 768 + 0 * 256 + gb * 16 + gc] = c.h;
    c.u = gisu[base + (size_t)BATCH * HDIM];       sGi2[0 * 768 + 1 * 256 + gb * 16 + gc] = c.h;
    c.u = gisu[base + 2 * (size_t)BATCH * HDIM];   sGi2[0 * 768 + 2 * 256 + gb * 16 + gc] = c.h;
  }
  uint4v w4a = {0, 0, 0, 0}, w4b = {0, 0, 0, 0};
  if (wid == 4 && lane < 48) {
    int gamma = lane >> 4, row = lane & 15;
    const char* sp = (const char*)(gisu + ((size_t)(3 + gamma) * BATCH + row0 + row) * HDIM + col0);
    asm volatile("global_load_dwordx4 %0, %2, off\n\t"
                 "global_load_dwordx4 %1, %2, off offset:16"
                 : "=v"(w4a), "=v"(w4b) : "v"(sp) : "memory");
  }
  __syncthreads();

  for (int t = 0; t < T_STEPS; ++t) {
    const int slot = t & 1;

    // ---- phase A (waves 0-3): per-wave poll + stage own sA quarter ----
    if (wid < 4) {
      if (t > 0) {
        const unsigned int* f1 = flags + g * 128 + lane;
        const unsigned int* f2 = f1 + 64;
        bool done = false;
        for (int it = 0; it < SPIN_MAX && !done; ++it) {
          unsigned int a, b;
          if (fast) {
            asm volatile("global_load_dword %0, %2, off sc0\n\t"
                         "global_load_dword %1, %3, off sc0\n\t"
                         "s_waitcnt vmcnt(0)"
                         : "=&v"(a), "=&v"(b) : "v"(f1), "v"(f2) : "memory");
          } else {
            asm volatile("global_load_dword %0, %2, off sc0 sc1\n\t"
                         "global_load_dword %1, %3, off sc0 sc1\n\t"
                         "s_waitcnt vmcnt(0)"
                         : "=&v"(a), "=&v"(b) : "v"(f1), "v"(f2) : "memory");
          }
          done = __all(a >= (unsigned)t && b >= (unsigned)t);
          if (!done && it > 48) __builtin_amdgcn_s_sleep(1);
        }
        // stage own quarter: rows wid*4..+3
        const int r  = (tid >> 4);           // 0..15 (tid<256)
        const int cb = (tid & 15) * 64;      // byte col
        const char* src = exb + (slot ^ 1) * EXSLOT + g * 16384 + r * 1024 + cb;
        uint4v v0, v1, v2, v3;
        if (fast) {
          asm volatile("global_load_dwordx4 %0, %4, off sc0\n\t"
                       "global_load_dwordx4 %1, %4, off offset:16 sc0\n\t"
                       "global_load_dwordx4 %2, %4, off offset:32 sc0\n\t"
                       "global_load_dwordx4 %3, %4, off offset:48 sc0\n\t"
                       "s_waitcnt vmcnt(0)"
                       : "=&v"(v0), "=&v"(v1), "=&v"(v2), "=&v"(v3)
                       : "v"(src) : "memory");
        } else {
          asm volatile("global_load_dwordx4 %0, %4, off sc0 sc1\n\t"
                       "global_load_dwordx4 %1, %4, off offset:16 sc0 sc1\n\t"
                       "global_load_dwordx4 %2, %4, off offset:32 sc0 sc1\n\t"
                       "global_load_dwordx4 %3, %4, off offset:48 sc0 sc1\n\t"
                       "s_waitcnt vmcnt(0)"
                       : "=&v"(v0), "=&v"(v1), "=&v"(v2), "=&v"(v3)
                       : "v"(src) : "memory");
        }
        __builtin_amdgcn_sched_barrier(0);
        int c0 = (tid & 15) * 32;
        half8 h0 = *reinterpret_cast<half8*>(&v0);
        half8 h1 = *reinterpret_cast<half8*>(&v1);
        half8 h2 = *reinterpret_cast<half8*>(&v2);
        half8 h3 = *reinterpret_cast<half8*>(&v3);
        half8 z = {(_Float16)0, (_Float16)0, (_Float16)0, (_Float16)0,
                   (_Float16)0, (_Float16)0, (_Float16)0, (_Float16)0};
        if ((sRstB[t] >> r) & 1u) { h0 = z; h1 = z; h2 = z; h3 = z; }
        *(half8*)&sA[r * LDK + c0 +  0] = h0;
        *(half8*)&sA[r * LDK + c0 +  8] = h1;
        *(half8*)&sA[r * LDK + c0 + 16] = h2;
        *(half8*)&sA[r * LDK + c0 + 24] = h3;
      } else {
        // t = 0: stage masked carry
        const float4* src = (const float4*)(carry + (size_t)row0 * HDIM);
        const unsigned int rm = sRstB[0];
        for (int i = tid; i < RW * 128; i += 256) {
          int r = i >> 7, c4 = i & 127;
          float4 v = src[(size_t)r * 128 + c4];
          float m = ((rm >> r) & 1u) ? 0.f : 1.f;
          half4v hv = {(_Float16)(v.x*m), (_Float16)(v.y*m),
                       (_Float16)(v.z*m), (_Float16)(v.w*m)};
          *(half4v*)&sA[r * LDK + c4 * 4] = hv;
        }
      }
    }
    __syncthreads();   // B2: sA staged

    // ---- phase B: gh GEMM (waves 0-2); wave 4: gi land + issue ----
    if (wid < 3) {
      const _Float16* ap = sA  + fr * LDK + kb;
      const _Float16* bp = sWh + (wid * 16 + fr) * LDK + kb;
      f32x4 a0 = {0.f, 0.f, 0.f, 0.f}, a1 = {0.f, 0.f, 0.f, 0.f};
#pragma unroll
      for (int kk = 0; kk < 16; kk += 2) {
        a0 = __builtin_amdgcn_mfma_f32_16x16x32_f16(
            *(const half8*)(ap + kk * 32), *(const half8*)(bp + kk * 32), a0, 0, 0, 0);
        a1 = __builtin_amdgcn_mfma_f32_16x16x32_f16(
            *(const half8*)(ap + (kk + 1) * 32), *(const half8*)(bp + (kk + 1) * 32), a1, 0, 0, 0);
      }
      a0 += a1;
      int crow = (lane >> 4) * 4;
      int ccol = wid * 16 + fr;
#pragma unroll
      for (int j = 0; j < 4; ++j) sGh[(crow + j) * LDG + ccol] = a0[j];
    } else if (wid == 4) {
      if (t + 1 < T_STEPS) {
        asm volatile("s_waitcnt vmcnt(0)" ::: "memory");   // own gi loads only
        __builtin_amdgcn_sched_barrier(0);
        if (lane < 48) {
          int gamma = lane >> 4, row = lane & 15;
          _Float16* d = &sGi2[((t + 1) & 1) * 768 + gamma * 256 + row * 16];
          *(uint4v*)d = w4a;
          *(uint4v*)(d + 8) = w4b;
        }
      }
      if (t + 2 < T_STEPS && lane < 48) {
        int gamma = lane >> 4, row = lane & 15;
        const char* sp = (const char*)(gisu + ((size_t)((t + 2) * 3 + gamma) * BATCH + row0 + row) * HDIM + col0);
        asm volatile("global_load_dwordx4 %0, %2, off\n\t"
                     "global_load_dwordx4 %1, %2, off offset:16"
                     : "=v"(w4a), "=v"(w4b) : "v"(sp) : "memory");
      }
    }
    __syncthreads();   // B3: sGh + sGi2 slot ready

    // ---- phase C (waves 0-3): gates + publish + per-wave drain + flag + ys ----
    if (tid < 256) {
      float gir = (float)sGi2[slot * 768 + 0 * 256 + gb * 16 + gc];
      float giz = (float)sGi2[slot * 768 + 1 * 256 + gb * 16 + gc];
      float gin = (float)sGi2[slot * 768 + 2 * 256 + gb * 16 + gc];
      float ghr = sGh[gb * LDG + gc]      + sBh[gc];
      float ghz = sGh[gb * LDG + 16 + gc] + sBh[16 + gc];
      float ghn = sGh[gb * LDG + 32 + gc] + sBh[32 + gc];
      float r = 1.f / (1.f + __expf(-(gir + ghr)));
      float z = 1.f / (1.f + __expf(-(giz + ghz)));
      float n = tanhf(gin + r * ghn);
      float hp = ((sRstB[t] >> gb) & 1u) ? 0.f : hreg;
      hreg = (1.f - z) * n + z * hp;

      if (t < T_STEPS - 1) {
        union { _Float16 h; unsigned short u; } pk;
        pk.h = (_Float16)hreg;
        unsigned int pv = (unsigned int)pk.u;
        char* dst = exb + slot * EXSLOT + g * 16384 + gb * 1024 + (col0 + gc) * 2;
        if (fast) asm volatile("global_store_short %0, %1, off sc0" :: "v"(dst), "v"(pv) : "memory");
        else      asm volatile("global_store_short %0, %1, off sc0 sc1" :: "v"(dst), "v"(pv) : "memory");
        asm volatile("s_waitcnt vmcnt(0)" ::: "memory");   // own wave's publish drained
        if (lane == 0) {
          unsigned int* fp = flags + g * 128 + p * 4 + wid;
          unsigned int val = (unsigned)(t + 1);
          if (fast) asm volatile("global_store_dword %0, %1, off sc0" :: "v"(fp), "v"(val) : "memory");
          else      asm volatile("global_store_dword %0, %1, off sc0 sc1" :: "v"(fp), "v"(val) : "memory");
        }
      }
      ys[((size_t)t * BATCH + row0 + gb) * HDIM + col0 + gc] = hreg;
      if (t == T_STEPS - 1)
        carryOut[(size_t)(row0 + gb) * HDIM + col0 + gc] = hreg;
    }
    // no barrier: sA/sGh overwrite next iter is fenced by B2(t+1); sGi2 double
    // buffer write (phase B) is fenced from gates reads by B2/B3 (see analysis)
  }

  __builtin_amdgcn_fence(__ATOMIC_RELEASE, "agent");
}

extern "C" void kernel_launch(void* const* d_in, const int* in_sizes, int n_in,
                              void* d_out, int out_size, void* d_ws, size_t ws_size,
                              hipStream_t stream) {
  const float* carry  = (const float*)d_in[0];
  const float* ins    = (const float*)d_in[1];
  const void*  resets = (const void*)d_in[2];
  const float* Wi     = (const float*)d_in[3];
  const float* Wh     = (const float*)d_in[4];
  const float* bh     = (const float*)d_in[5];
  float* out = (float*)d_out;

  unsigned int* wsb  = (unsigned int*)d_ws;
  unsigned int* dec  = (unsigned int*)((char*)d_ws + DEC_OFF);
  unsigned int* ex0  = (unsigned int*)((char*)d_ws + EX_OFF);
  unsigned int* ex1  = ex0 + EX_DWORDS;
  _Float16*     gis  = (_Float16*)((char*)d_ws + GI_OFF);

  (void)hipMemsetAsync(d_ws, 0, MEMSET_BYTES, stream);

  sniff_kernel<<<dim3(1), dim3(256), 0, stream>>>(
      (const unsigned int*)resets, dec);

  const bool bigWs = ws_size >= (size_t)GI_OFF + GI_BYTES;

  if (bigWs) {
    gi_prepass2<<<dim3(256), dim3(256), 0, stream>>>(ins, Wi, gis);
    void* args[] = { (void*)&carry, (void*)&resets, (void*)&Wh, (void*)&bh,
                     (void*)&out, (void*)&wsb, (void*)&gis, (void*)&dec };
    (void)hipLaunchCooperativeKernel((const void*)gru_kernel_v8,
                                     dim3(256), dim3(THREADS8),
                                     args, 0, stream);
  } else {
    void* args[] = { (void*)&carry, (void*)&ins, (void*)&resets, (void*)&Wi,
                     (void*)&Wh, (void*)&bh, (void*)&out, (void*)&wsb,
                     (void*)&ex0, (void*)&ex1, (void*)&dec };
    (void)hipLaunchCooperativeKernel((const void*)gru_kernel_v1,
                                     dim3(NGROUP * NSLICE), dim3(THREADS),
                                     args, 0, stream);
  }
}

// Round 13
// 2176.741 us; speedup vs baseline: 2.0883x; 2.0883x over previous
//
#include <hip/hip_runtime.h>

#define T_STEPS 512
#define BATCH   128
#define DIN     512
#define HDIM    512
#define THREEH  1536
#define THREADS 256
#define LDK     520    // padded K stride in halves
#define LDG     49
#define SPIN_MAX (1 << 16)   // bounded spin: wedge -> wrong answer, never hang
#define HS_SPIN  512
// v1 fallback geometry (small-ws)
#define NGROUP  4
#define NSLICE  32
#define BC      32
#define HC      16
#define NC      48
#define CNT_STRIDE 16
#define EX_DWORDS (NSLICE * BATCH * HC / 2)
// v9 geometry: 8 cohorts x 16 rows; 32 slices x 16 cols; 256 threads
#define RW 16
#define EXSLOT 131072        // 8g x 16r x 512c x 2B
// ws layout (first 8KB memset each launch)
#define FLAGS_OFF  0         // 8 cohorts x 32 slice-flags (also v1 cnt area)
#define GBAR_OFF   4096      // 8 counters x 64B
#define NONCE_OFF  4608
#define DEC_OFF    4736
#define VD_OFF     5120      // 256 uints
#define HS_OFF     6144      // 256 uints
#define MEMSET_BYTES 8192
#define EX_OFF     8192      // 2 x 128KB exchange
#define GI_OFF     (1u<<20)
#define GI_BYTES   201326592ULL
// blocked gis: [t][gamma][slice(32)][b(128)][c(16)] fp16
#define GI_GSTRIDE ((size_t)32 * 128 * 16)   // gamma stride in elems

typedef _Float16 half8 __attribute__((ext_vector_type(8)));
typedef _Float16 half4v __attribute__((ext_vector_type(4)));
typedef float    f32x4 __attribute__((ext_vector_type(4)));
typedef unsigned int uint4v __attribute__((ext_vector_type(4)));

__global__ void sniff_kernel(const unsigned int* __restrict__ w,
                             unsigned int* __restrict__ dec) {
  unsigned int local = 0;
  for (int i = threadIdx.x; i < (T_STEPS * BATCH) / 4; i += 256) {
    if (w[i] > 1u) local = 1u;
  }
  if (local) atomicOr(dec, 1u);
}

// ======================= v1 fallback (round-4, proven; small-ws only) =======================
__device__ __forceinline__ void run_gemm(const _Float16* __restrict__ sAa,
                                         const _Float16* __restrict__ sW,
                                         float* __restrict__ sAcc,
                                         int wid, int lane) {
  const int fr = lane & 15;
  const int kb = (lane >> 4) * 8;
  for (int tile = wid; tile < 6; tile += 4) {
    int mi = tile / 3, ni = tile - mi * 3;
    const _Float16* ap = sAa + (mi * 16 + fr) * LDK + kb;
    const _Float16* bp = sW  + (ni * 16 + fr) * LDK + kb;
    f32x4 acc = {0.f, 0.f, 0.f, 0.f};
#pragma unroll
    for (int kk = 0; kk < DIN / 32; ++kk)
      acc = __builtin_amdgcn_mfma_f32_16x16x32_f16(
          *(const half8*)(ap + kk * 32),
          *(const half8*)(bp + kk * 32), acc, 0, 0, 0);
    int crow = mi * 16 + (lane >> 4) * 4;
    int ccol = ni * 16 + fr;
#pragma unroll
    for (int j = 0; j < 4; ++j) sAcc[(crow + j) * LDG + ccol] = acc[j];
  }
}

__global__ __launch_bounds__(THREADS, 1)
void gru_kernel_v1(const float* __restrict__ carry,
                   const float* __restrict__ ins,
                   const void*  __restrict__ resets_raw,
                   const float* __restrict__ Wi,
                   const float* __restrict__ Wh,
                   const float* __restrict__ bh,
                   float* __restrict__ out,
                   unsigned int* __restrict__ cnt,
                   unsigned int* __restrict__ ex0,
                   unsigned int* __restrict__ ex1,
                   const unsigned int* __restrict__ dec)
{
  __shared__ alignas(16) _Float16 sWi[NC * LDK];
  __shared__ alignas(16) _Float16 sWh[NC * LDK];
  __shared__ alignas(16) _Float16 sA [BC * LDK];
  __shared__ float sGi[BC * LDG];
  __shared__ float sGh[BC * LDG];
  __shared__ float sBh[NC];
  __shared__ int   sRst[BC];

  const int tid  = threadIdx.x;
  const int bid  = blockIdx.x;
  const int g    = bid & (NGROUP - 1);
  const int p    = bid >> 2;
  const int row0 = g * BC;
  const int col0 = p * HC;

  float* carryOut = out;
  float* ys = out + BATCH * HDIM;

  const unsigned int isBool = *dec;
  const unsigned char* r8  = (const unsigned char*)resets_raw;
  const int*           r32 = (const int*)resets_raw;

  unsigned int* ex[2] = { ex0, ex1 };
  unsigned int* myCnt = cnt + g * CNT_STRIDE;

  for (int idx = tid; idx < DIN * NC; idx += THREADS) {
    int k  = idx / NC;
    int ci = idx - k * NC;
    int gcol = (ci >> 4) * HDIM + col0 + (ci & 15);
    sWi[ci * LDK + k] = (_Float16)Wi[k * THREEH + gcol];
    sWh[ci * LDK + k] = (_Float16)Wh[k * THREEH + gcol];
  }
  if (tid < NC) {
    int gcol = (tid >> 4) * HDIM + col0 + (tid & 15);
    sBh[tid] = bh[gcol];
  }

  float hreg[2];
  {
    int idx = tid * 2;
    int b0 = idx >> 4, c0 = idx & 15;
    hreg[0] = carry[(size_t)(row0 + b0) * HDIM + col0 + c0];
    hreg[1] = carry[(size_t)(row0 + b0) * HDIM + col0 + c0 + 1];
  }

  const int wid  = tid >> 6;
  const int lane = tid & 63;

  auto stageRst = [&](int t) {
    if (tid < BC) {
      int off = t * BATCH + row0 + tid;
      sRst[tid] = isBool ? (int)r8[off] : r32[off];
    }
  };
  auto stageX = [&](int t) {
    const float4* src = (const float4*)(ins + (size_t)(t * BATCH + row0) * DIN);
    for (int i = tid; i < BC * (DIN / 4); i += THREADS) {
      int r = i >> 7, c4 = i & 127;
      float4 v = src[(size_t)r * 128 + c4];
      half4v hv = {(_Float16)v.x, (_Float16)v.y, (_Float16)v.z, (_Float16)v.w};
      *(half4v*)&sA[r * LDK + c4 * 4] = hv;
    }
  };

  stageRst(0);
  stageX(0);
  __syncthreads();
  run_gemm(sA, sWi, sGi, wid, lane);
  __syncthreads();
  {
    const float4* src = (const float4*)(carry + (size_t)row0 * HDIM);
    for (int i = tid; i < BC * (HDIM / 4); i += THREADS) {
      int r = i >> 7, c4 = i & 127;
      float4 v = src[(size_t)r * 128 + c4];
      float m = sRst[r] ? 0.f : 1.f;
      half4v hv = {(_Float16)(v.x*m), (_Float16)(v.y*m),
                   (_Float16)(v.z*m), (_Float16)(v.w*m)};
      *(half4v*)&sA[r * LDK + c4 * 4] = hv;
    }
  }
  __syncthreads();

  for (int t = 0; t < T_STEPS; ++t) {
    if (t > 0) {
      {
        const unsigned int target = 32u * (unsigned)t;
        unsigned int fv;
        for (int it = 0; it < SPIN_MAX; ++it) {
          asm volatile("global_load_dword %0, %1, off sc0 sc1\n\t"
                       "s_waitcnt vmcnt(0)"
                       : "=v"(fv) : "v"(myCnt) : "memory");
          if (fv >= target) break;
          __builtin_amdgcn_s_sleep(1);
        }
      }
      {
        const unsigned int* exsrc = ex[(t - 1) & 1];
        uint4v vv[8];
#pragma unroll
        for (int j = 0; j < 8; ++j) {
          int i = tid + THREADS * j;
          int p_ = i >> 6, b_ = (i >> 1) & 31, hw = (i & 1) << 2;
          const unsigned int* sp = exsrc + p_ * 1024 + (row0 + b_) * 8 + hw;
          asm volatile("global_load_dwordx4 %0, %1, off sc0 sc1"
                       : "=&v"(vv[j]) : "v"(sp) : "memory");
        }
        asm volatile("s_waitcnt vmcnt(0)" ::: "memory");
        __builtin_amdgcn_sched_barrier(0);
#pragma unroll
        for (int j = 0; j < 8; ++j) {
          int i = tid + THREADS * j;
          int p_ = i >> 6, b_ = (i >> 1) & 31, hw = (i & 1) << 3;
          half8 hv = *reinterpret_cast<half8*>(&vv[j]);
          half8 z = {(_Float16)0, (_Float16)0, (_Float16)0, (_Float16)0,
                     (_Float16)0, (_Float16)0, (_Float16)0, (_Float16)0};
          hv = sRst[b_] ? z : hv;
          *(half8*)&sA[b_ * LDK + p_ * 16 + hw] = hv;
        }
      }
      __syncthreads();
    }

    run_gemm(sA, sWh, sGh, wid, lane);
    __syncthreads();

    {
#pragma unroll
      for (int e = 0; e < 2; ++e) {
        int idx = tid * 2 + e;
        int b = idx >> 4, cj = idx & 15;
        float gir = sGi[b * LDG + cj];
        float giz = sGi[b * LDG + 16 + cj];
        float gin = sGi[b * LDG + 32 + cj];
        float ghr = sGh[b * LDG + cj]      + sBh[cj];
        float ghz = sGh[b * LDG + 16 + cj] + sBh[16 + cj];
        float ghn = sGh[b * LDG + 32 + cj] + sBh[32 + cj];
        float r = 1.f / (1.f + __expf(-(gir + ghr)));
        float z = 1.f / (1.f + __expf(-(giz + ghz)));
        float n = tanhf(gin + r * ghn);
        float hp = sRst[b] ? 0.f : hreg[e];
        hreg[e] = (1.f - z) * n + z * hp;
      }
      union { _Float16 h[2]; unsigned int u; } pk;
      pk.h[0] = (_Float16)hreg[0];
      pk.h[1] = (_Float16)hreg[1];
      unsigned int* dst = ex[t & 1] + p * 1024 + (row0 + (tid >> 3)) * 8 + (tid & 7);
      asm volatile("global_store_dword %0, %1, off sc0 sc1"
                   :: "v"(dst), "v"(pk.u) : "memory");
      int b0 = (tid * 2) >> 4, c0 = (tid * 2) & 15;
      float2 yv = make_float2(hreg[0], hreg[1]);
      *(float2*)&ys[((size_t)t * BATCH + row0 + b0) * HDIM + col0 + c0] = yv;
      if (t == T_STEPS - 1)
        *(float2*)&carryOut[(size_t)(row0 + b0) * HDIM + col0 + c0] = yv;
    }
    asm volatile("s_waitcnt vmcnt(0)" ::: "memory");
    __syncthreads();
    if (tid == 0) atomicAdd(myCnt, 1u);

    if (t < T_STEPS - 1) {
      stageRst(t + 1);
      stageX(t + 1);
      __syncthreads();
      run_gemm(sA, sWi, sGi, wid, lane);
      __syncthreads();
    }
  }
}

// ============ gi prepass v3: blocked output layout, coalesced stores ============
// gis[t][gamma][slice(32)][b(128)][c(16)] fp16: each C-tile lands contiguous.
__global__ __launch_bounds__(256, 1)
void gi_prepass3(const float* __restrict__ ins,
                 const float* __restrict__ Wi,
                 _Float16* __restrict__ gis)
{
  __shared__ alignas(16) _Float16 sWiT[48 * LDK];
  __shared__ alignas(16) _Float16 sX[32 * LDK];

  const int tid = threadIdx.x;
  const int bid = blockIdx.x;
  const int n   = bid >> 3;    // col-slice 0..31
  const int mg  = bid & 7;     // M-stripe of 8192 rows
  const int wid = tid >> 6;
  const int lane = tid & 63;
  const int fr = lane & 15;
  const int kb = (lane >> 4) * 8;

  for (int idx = tid; idx < 48 * DIN; idx += 256) {
    int ci = idx % 48, k = idx / 48;
    int gcol = (ci >> 4) * HDIM + n * 16 + (ci & 15);
    sWiT[ci * LDK + k] = (_Float16)Wi[(size_t)k * THREEH + gcol];
  }

  float4 va[16];
  auto LOADS = [&](int ch) {
    const float4* src = (const float4*)(ins + (size_t)(mg * 8192 + ch * 32) * DIN);
#pragma unroll
    for (int j = 0; j < 16; ++j) va[j] = src[tid + 256 * j];
  };
  auto WRITE = [&]() {
#pragma unroll
    for (int j = 0; j < 16; ++j) {
      int i = tid + 256 * j;
      int r = i >> 7, c4 = i & 127;
      float4 v = va[j];
      half4v hv = {(_Float16)v.x, (_Float16)v.y, (_Float16)v.z, (_Float16)v.w};
      *(half4v*)&sX[r * LDK + c4 * 4] = hv;
    }
  };

  LOADS(0);
  for (int ch = 0; ch < 256; ++ch) {
    WRITE();
    __syncthreads();
    if (ch + 1 < 256) LOADS(ch + 1);

    const int m0 = mg * 8192 + ch * 32;
    const int tt = m0 >> 7;            // step (32-row chunk never crosses t)
    const int bb0 = m0 & 127;
    for (int tile = wid; tile < 6; tile += 4) {
      int mi = tile / 3, ni = tile - mi * 3;
      const _Float16* ap = sX   + (mi * 16 + fr) * LDK + kb;
      const _Float16* bp = sWiT + (ni * 16 + fr) * LDK + kb;
      f32x4 acc = {0.f, 0.f, 0.f, 0.f};
#pragma unroll
      for (int kk = 0; kk < DIN / 32; ++kk)
        acc = __builtin_amdgcn_mfma_f32_16x16x32_f16(
            *(const half8*)(ap + kk * 32),
            *(const half8*)(bp + kk * 32), acc, 0, 0, 0);
      int gr = mi * 16 + ((lane >> 4) << 2);
      size_t cbase = (((size_t)(tt * 3 + ni) * 32 + n) * 128) * 16;
#pragma unroll
      for (int j = 0; j < 4; ++j)
        gis[cbase + (size_t)(bb0 + gr + j) * 16 + fr] = (_Float16)acc[j];
    }
    __syncthreads();
  }
}

// ============ v9: round-8 v4 body + nonce handshake + epoch'd flags ============
__device__ __forceinline__ void gridbar9(unsigned int* ctr, int tid) {
  __syncthreads();
  if (tid == 0) {
    atomicAdd(ctr, 1u);
    unsigned int v;
    for (int it = 0; it < SPIN_MAX; ++it) {
      asm volatile("global_load_dword %0, %1, off sc0 sc1\n\t"
                   "s_waitcnt vmcnt(0)" : "=v"(v) : "v"(ctr) : "memory");
      if (v >= 256u) break;
      __builtin_amdgcn_s_sleep(1);
    }
  }
  __syncthreads();
}

__global__ __launch_bounds__(THREADS, 1)
void gru_kernel_v9(const float* __restrict__ carry,
                   const void*  __restrict__ resets_raw,
                   const float* __restrict__ Wh,
                   const float* __restrict__ bh,
                   float* __restrict__ out,
                   unsigned int* __restrict__ wsb,
                   const _Float16* __restrict__ gis,
                   const unsigned int* __restrict__ dec)
{
  __shared__ alignas(16) _Float16 sWh[NC * LDK];   // ~50KB
  __shared__ alignas(16) _Float16 sA [RW * LDK];   // ~16.6KB
  __shared__ float sGh[RW * LDG];
  __shared__ float sBh[NC];
  __shared__ int   sRst[RW];
  __shared__ int   sFast;
  __shared__ unsigned int sNonce;

  const int tid  = threadIdx.x;
  const int bid  = blockIdx.x;
  const int g    = bid & 7;        // cohort (presumed XCD)
  const int p    = bid >> 3;       // col slice 0..31
  const int row0 = g * RW;
  const int col0 = p * HC;

  unsigned int* flags    = wsb + (FLAGS_OFF / 4);   // [g*32+p]
  unsigned int* gbars    = wsb + (GBAR_OFF / 4);
  unsigned int* nonceArr = wsb + (NONCE_OFF / 4);
  unsigned int* vd       = wsb + (VD_OFF / 4);
  unsigned int* hs       = wsb + (HS_OFF / 4);
  char*         exb      = (char*)wsb + EX_OFF;

  float* carryOut = out;
  float* ys = out + BATCH * HDIM;

  const unsigned int isBool = *dec;
  const unsigned char* r8  = (const unsigned char*)resets_raw;
  const int*           r32 = (const int*)resets_raw;
  const unsigned short* gisu = (const unsigned short*)gis;

  const int wid  = tid >> 6;
  const int lane = tid & 63;
  const int fr   = lane & 15;
  const int kb   = (lane >> 4) * 8;
  const int gb   = tid >> 4;       // batch row 0..15
  const int gc   = tid & 15;       // col 0..15

  // ---- weights / bias ----
  for (int idx = tid; idx < DIN * NC; idx += THREADS) {
    int k  = idx / NC;
    int ci = idx - k * NC;
    int gcol = (ci >> 4) * HDIM + col0 + (ci & 15);
    sWh[ci * LDK + k] = (_Float16)Wh[(size_t)k * THREEH + gcol];
  }
  if (tid < NC) {
    int gcol = (tid >> 4) * HDIM + col0 + (tid & 15);
    sBh[tid] = bh[gcol];
  }
  float hreg = carry[(size_t)(row0 + gb) * HDIM + col0 + gc];

  // ---- nonce handshake (poll-until-match, proven in r9/r11/r12) ----
  if (p == 0 && tid == 0) {
    unsigned long long tv = __builtin_amdgcn_s_memrealtime();
    unsigned int nv = (unsigned int)(tv ^ (tv >> 32));
    if (nv == 0) nv = 0x5A5A5A5Au;
    asm volatile("global_store_dword %0, %1, off sc0 sc1\n\t"
                 "s_waitcnt vmcnt(0)" :: "v"(nonceArr + g), "v"(nv) : "memory");
  }
  gridbar9(gbars + 0 * 16, tid);
  if (tid == 0) {
    unsigned int nv;
    asm volatile("global_load_dword %0, %1, off sc0 sc1\n\t"
                 "s_waitcnt vmcnt(0)" : "=v"(nv) : "v"(nonceArr + g) : "memory");
    sNonce = nv;
  }
  __syncthreads();
  const unsigned int nonce = sNonce;
  unsigned int ep16 = (nonce >> 16) ^ (nonce & 0xFFFFu);
  if (ep16 == 0) ep16 = 0xA5A5u;      // epoch tag, never 0

  bool okAll = true;
  for (int r = 0; r < 2; ++r) {
    if (tid == 0) {
      unsigned int tok = nonce ^ ((unsigned)p << 8) ^ ((unsigned)(r + 1) << 20);
      asm volatile("global_store_dword %0, %1, off sc0\n\t"
                   "s_waitcnt vmcnt(0)" :: "v"(hs + bid), "v"(tok) : "memory");
    }
    __syncthreads();
    if (tid < 32) {
      unsigned int expv = nonce ^ ((unsigned)tid << 8) ^ ((unsigned)(r + 1) << 20);
      const unsigned int* hp = hs + (g + 8 * tid);
      bool got = false;
      for (int it = 0; it < HS_SPIN && !got; ++it) {
        unsigned int v;
        asm volatile("global_load_dword %0, %1, off sc0\n\t"
                     "s_waitcnt vmcnt(0)" : "=v"(v) : "v"(hp) : "memory");
        got = (v == expv);
      }
      okAll = okAll && got;
    }
    gridbar9(gbars + (1 + r) * 16, tid);
  }
  {
    bool wgok = __all((tid < 32) ? okAll : true);
    if (tid == 0) {
      unsigned int vv = wgok ? 1u : 0u;
      asm volatile("global_store_dword %0, %1, off sc0 sc1\n\t"
                   "s_waitcnt vmcnt(0)" :: "v"(vd + bid), "v"(vv) : "memory");
    }
    gridbar9(gbars + 3 * 16, tid);
    bool fin = true;
    if (tid < 32) {
      unsigned int v;
      asm volatile("global_load_dword %0, %1, off sc0 sc1\n\t"
                   "s_waitcnt vmcnt(0)" : "=v"(v) : "v"(vd + (g + 8 * tid)) : "memory");
      fin = (v == 1u);
    }
    bool unan = __all((tid < 32) ? fin : true);
    if (tid == 0) sFast = unan ? 1 : 0;
    __syncthreads();
  }
  const int fast = sFast;

  // ---- prologue: rst(0) + masked-carry stage into sA ----
  if (tid < RW) {
    int off = row0 + tid;
    sRst[tid] = isBool ? (int)r8[off] : r32[off];
  }
  __syncthreads();
  {
    const float4* src = (const float4*)(carry + (size_t)row0 * HDIM);
    for (int i = tid; i < RW * 128; i += THREADS) {
      int r = i >> 7, c4 = i & 127;
      float4 v = src[(size_t)r * 128 + c4];
      float m = sRst[r] ? 0.f : 1.f;
      half4v hv = {(_Float16)(v.x*m), (_Float16)(v.y*m),
                   (_Float16)(v.z*m), (_Float16)(v.w*m)};
      *(half4v*)&sA[r * LDK + c4 * 4] = hv;
    }
  }

  for (int t = 0; t < T_STEPS; ++t) {
    const int slot = t & 1;
    // gi loads (blocked layout; recurrence-independent, drained with the wait)
    unsigned short gu0, gu1, gu2;
    {
      size_t gbase = (((size_t)(t * 3) * 32 + p) * 128 + row0 + gb) * 16 + gc;
      gu0 = gisu[gbase];
      gu1 = gisu[gbase + GI_GSTRIDE];
      gu2 = gisu[gbase + 2 * GI_GSTRIDE];
    }
    if (t > 0 && tid < RW) {
      int off = t * BATCH + row0 + tid;
      sRst[tid] = isBool ? (int)r8[off] : r32[off];
    }
    // wait: epoch'd flags, 32 lanes poll one 128B line
    if (t > 0) {
      const unsigned int exp_ = (ep16 << 16) | (unsigned)t;
      bool done = false;
      const unsigned int* fp = flags + (g * 32 + (tid & 31));
      for (int it = 0; it < SPIN_MAX && !done; ++it) {
        unsigned int fv = 0xFFFFFFFFu;
        bool ok = true;
        if (tid < 32) {
          if (fast) {
            asm volatile("global_load_dword %0, %1, off sc0\n\t"
                         "s_waitcnt vmcnt(0)" : "=v"(fv) : "v"(fp) : "memory");
          } else {
            asm volatile("global_load_dword %0, %1, off sc0 sc1\n\t"
                         "s_waitcnt vmcnt(0)" : "=v"(fv) : "v"(fp) : "memory");
          }
          ok = ((fv >> 16) == ep16) && ((fv & 0xFFFFu) >= (unsigned)t);
        }
        done = __all(ok);
        if (!done) __builtin_amdgcn_s_sleep(1);
        (void)exp_;
      }
    }
    __syncthreads();

    if (t > 0) {
      // stage h_{t-1}: 16KB from cohort-local exchange
      const char* src = exb + (slot ^ 1) * EXSLOT + g * 16384
                      + (tid >> 4) * 1024 + (tid & 15) * 64;
      uint4v v0, v1, v2, v3;
      if (fast) {
        asm volatile("global_load_dwordx4 %0, %4, off sc0\n\t"
                     "global_load_dwordx4 %1, %4, off offset:16 sc0\n\t"
                     "global_load_dwordx4 %2, %4, off offset:32 sc0\n\t"
                     "global_load_dwordx4 %3, %4, off offset:48 sc0\n\t"
                     "s_waitcnt vmcnt(0)"
                     : "=&v"(v0), "=&v"(v1), "=&v"(v2), "=&v"(v3)
                     : "v"(src) : "memory");
      } else {
        asm volatile("global_load_dwordx4 %0, %4, off sc0 sc1\n\t"
                     "global_load_dwordx4 %1, %4, off offset:16 sc0 sc1\n\t"
                     "global_load_dwordx4 %2, %4, off offset:32 sc0 sc1\n\t"
                     "global_load_dwordx4 %3, %4, off offset:48 sc0 sc1\n\t"
                     "s_waitcnt vmcnt(0)"
                     : "=&v"(v0), "=&v"(v1), "=&v"(v2), "=&v"(v3)
                     : "v"(src) : "memory");
      }
      __builtin_amdgcn_sched_barrier(0);
      int r = tid >> 4, c0 = (tid & 15) * 32;
      half8 h0 = *reinterpret_cast<half8*>(&v0);
      half8 h1 = *reinterpret_cast<half8*>(&v1);
      half8 h2 = *reinterpret_cast<half8*>(&v2);
      half8 h3 = *reinterpret_cast<half8*>(&v3);
      half8 z = {(_Float16)0, (_Float16)0, (_Float16)0, (_Float16)0,
                 (_Float16)0, (_Float16)0, (_Float16)0, (_Float16)0};
      if (sRst[r]) { h0 = z; h1 = z; h2 = z; h3 = z; }
      *(half8*)&sA[r * LDK + c0 +  0] = h0;
      *(half8*)&sA[r * LDK + c0 +  8] = h1;
      *(half8*)&sA[r * LDK + c0 + 16] = h2;
      *(half8*)&sA[r * LDK + c0 + 24] = h3;
      __syncthreads();
    }

    // gh GEMM: M=16, 3 N-tiles over waves 0..2 (split-K pair)
    if (wid < 3) {
      const _Float16* ap = sA  + fr * LDK + kb;
      const _Float16* bp = sWh + (wid * 16 + fr) * LDK + kb;
      f32x4 a0 = {0.f, 0.f, 0.f, 0.f}, a1 = {0.f, 0.f, 0.f, 0.f};
#pragma unroll
      for (int kk = 0; kk < DIN / 32; kk += 2) {
        a0 = __builtin_amdgcn_mfma_f32_16x16x32_f16(
            *(const half8*)(ap + kk * 32), *(const half8*)(bp + kk * 32), a0, 0, 0, 0);
        a1 = __builtin_amdgcn_mfma_f32_16x16x32_f16(
            *(const half8*)(ap + (kk + 1) * 32), *(const half8*)(bp + (kk + 1) * 32), a1, 0, 0, 0);
      }
      a0 += a1;
      int crow = (lane >> 4) * 4;
      int ccol = wid * 16 + fr;
#pragma unroll
      for (int j = 0; j < 4; ++j) sGh[(crow + j) * LDG + ccol] = a0[j];
    }
    __syncthreads();

    // gates (1 elem/thread) + publish
    {
      union { unsigned short u; _Float16 h; } c0_, c1_, c2_;
      c0_.u = gu0; c1_.u = gu1; c2_.u = gu2;
      float gir = (float)c0_.h;
      float giz = (float)c1_.h;
      float gin = (float)c2_.h;
      float ghr = sGh[gb * LDG + gc]      + sBh[gc];
      float ghz = sGh[gb * LDG + 16 + gc] + sBh[16 + gc];
      float ghn = sGh[gb * LDG + 32 + gc] + sBh[32 + gc];
      float r = 1.f / (1.f + __expf(-(gir + ghr)));
      float z = 1.f / (1.f + __expf(-(giz + ghz)));
      float n = tanhf(gin + r * ghn);
      float hp = sRst[gb] ? 0.f : hreg;
      hreg = (1.f - z) * n + z * hp;

      if (t < T_STEPS - 1) {
        union { _Float16 h; unsigned short u; } pk;
        pk.h = (_Float16)hreg;
        unsigned int pv = (unsigned int)pk.u;
        unsigned short* dst = (unsigned short*)
          (exb + slot * EXSLOT + g * 16384 + gb * 1024 + (col0 + gc) * 2);
        if (fast) {
          asm volatile("global_store_short %0, %1, off sc0"
                       :: "v"(dst), "v"(pv) : "memory");
        } else {
          asm volatile("global_store_short %0, %1, off sc0 sc1"
                       :: "v"(dst), "v"(pv) : "memory");
        }
      }
    }
    asm volatile("s_waitcnt vmcnt(0)" ::: "memory");   // publish drained
    __syncthreads();                                   // all waves drained
    if (tid == 0 && t < T_STEPS - 1) {
      unsigned int* fp = flags + (g * 32 + p);
      unsigned int val = (ep16 << 16) | (unsigned)(t + 1);
      if (fast) {
        asm volatile("global_store_dword %0, %1, off sc0"
                     :: "v"(fp), "v"(val) : "memory");
      } else {
        asm volatile("global_store_dword %0, %1, off sc0 sc1"
                     :: "v"(fp), "v"(val) : "memory");
      }
    }
    // ys (write-only) after the flag, off the critical path
    {
      ys[((size_t)t * BATCH + row0 + gb) * HDIM + col0 + gc] = hreg;
      if (t == T_STEPS - 1)
        carryOut[(size_t)(row0 + gb) * HDIM + col0 + gc] = hreg;
    }
  }

  // flush dirty L2 lines so no stale data leaks into a later replay
  __builtin_amdgcn_fence(__ATOMIC_RELEASE, "agent");
}

extern "C" void kernel_launch(void* const* d_in, const int* in_sizes, int n_in,
                              void* d_out, int out_size, void* d_ws, size_t ws_size,
                              hipStream_t stream) {
  const float* carry  = (const float*)d_in[0];
  const float* ins    = (const float*)d_in[1];
  const void*  resets = (const void*)d_in[2];
  const float* Wi     = (const float*)d_in[3];
  const float* Wh     = (const float*)d_in[4];
  const float* bh     = (const float*)d_in[5];
  float* out = (float*)d_out;

  unsigned int* wsb  = (unsigned int*)d_ws;
  unsigned int* dec  = (unsigned int*)((char*)d_ws + DEC_OFF);
  unsigned int* ex0  = (unsigned int*)((char*)d_ws + EX_OFF);
  unsigned int* ex1  = ex0 + EX_DWORDS;
  _Float16*     gis  = (_Float16*)((char*)d_ws + GI_OFF);

  (void)hipMemsetAsync(d_ws, 0, MEMSET_BYTES, stream);

  sniff_kernel<<<dim3(1), dim3(256), 0, stream>>>(
      (const unsigned int*)resets, dec);

  const bool bigWs = ws_size >= (size_t)GI_OFF + GI_BYTES;

  if (bigWs) {
    gi_prepass3<<<dim3(256), dim3(256), 0, stream>>>(ins, Wi, gis);
    void* args[] = { (void*)&carry, (void*)&resets, (void*)&Wh, (void*)&bh,
                     (void*)&out, (void*)&wsb, (void*)&gis, (void*)&dec };
    (void)hipLaunchCooperativeKernel((const void*)gru_kernel_v9,
                                     dim3(256), dim3(THREADS),
                                     args, 0, stream);
  } else {
    void* args[] = { (void*)&carry, (void*)&ins, (void*)&resets, (void*)&Wi,
                     (void*)&Wh, (void*)&bh, (void*)&out, (void*)&wsb,
                     (void*)&ex0, (void*)&ex1, (void*)&dec };
    (void)hipLaunchCooperativeKernel((const void*)gru_kernel_v1,
                                     dim3(NGROUP * NSLICE), dim3(THREADS),
                                     args, 0, stream);
  }
}

// Round 15
// 2172.297 us; speedup vs baseline: 2.0925x; 1.0020x over previous
//
#include <hip/hip_runtime.h>

#define T_STEPS 512
#define BATCH   128
#define DIN     512
#define HDIM    512
#define THREEH  1536
#define THREADS 256
#define LDK     520    // padded K stride in halves
#define LDG     49
#define SPIN_MAX (1 << 16)   // bounded spin: wedge -> wrong answer, never hang
#define HS_SPIN  512
// v1 fallback geometry (small-ws)
#define NGROUP  4
#define NSLICE  32
#define BC      32
#define HC      16
#define NC      48
#define CNT_STRIDE 16
#define EX_DWORDS (NSLICE * BATCH * HC / 2)
// v9 geometry: 8 cohorts x 16 rows; 32 slices x 16 cols; 256 threads
#define RW 16
#define EXSLOT 131072        // 8g x 16r x 512c x 2B
// ws layout (first 8KB memset each launch)
#define FLAGS_OFF  0         // 8 cohorts x 32 slice-flags (also v1 cnt area)
#define GBAR_OFF   4096      // 8 counters x 64B
#define NONCE_OFF  4608
#define DEC_OFF    4736
#define VD_OFF     5120      // 256 uints
#define HS_OFF     6144      // 256 uints
#define MEMSET_BYTES 8192
#define EX_OFF     8192      // 2 x 128KB exchange
#define GI_OFF     (1u<<20)
#define GI_BYTES   201326592ULL
// blocked gis: [t][gamma][slice(32)][b(128)][c(16)] fp16
#define GI_GSTRIDE ((size_t)32 * 128 * 16)   // gamma stride in elems

typedef _Float16 half8 __attribute__((ext_vector_type(8)));
typedef _Float16 half4v __attribute__((ext_vector_type(4)));
typedef float    f32x4 __attribute__((ext_vector_type(4)));
typedef unsigned int uint4v __attribute__((ext_vector_type(4)));

__global__ void sniff_kernel(const unsigned int* __restrict__ w,
                             unsigned int* __restrict__ dec) {
  unsigned int local = 0;
  for (int i = threadIdx.x; i < (T_STEPS * BATCH) / 4; i += 256) {
    if (w[i] > 1u) local = 1u;
  }
  if (local) atomicOr(dec, 1u);
}

// ======================= v1 fallback (round-4, proven; small-ws only) =======================
__device__ __forceinline__ void run_gemm(const _Float16* __restrict__ sAa,
                                         const _Float16* __restrict__ sW,
                                         float* __restrict__ sAcc,
                                         int wid, int lane) {
  const int fr = lane & 15;
  const int kb = (lane >> 4) * 8;
  for (int tile = wid; tile < 6; tile += 4) {
    int mi = tile / 3, ni = tile - mi * 3;
    const _Float16* ap = sAa + (mi * 16 + fr) * LDK + kb;
    const _Float16* bp = sW  + (ni * 16 + fr) * LDK + kb;
    f32x4 acc = {0.f, 0.f, 0.f, 0.f};
#pragma unroll
    for (int kk = 0; kk < DIN / 32; ++kk)
      acc = __builtin_amdgcn_mfma_f32_16x16x32_f16(
          *(const half8*)(ap + kk * 32),
          *(const half8*)(bp + kk * 32), acc, 0, 0, 0);
    int crow = mi * 16 + (lane >> 4) * 4;
    int ccol = ni * 16 + fr;
#pragma unroll
    for (int j = 0; j < 4; ++j) sAcc[(crow + j) * LDG + ccol] = acc[j];
  }
}

__global__ __launch_bounds__(THREADS, 1)
void gru_kernel_v1(const float* __restrict__ carry,
                   const float* __restrict__ ins,
                   const void*  __restrict__ resets_raw,
                   const float* __restrict__ Wi,
                   const float* __restrict__ Wh,
                   const float* __restrict__ bh,
                   float* __restrict__ out,
                   unsigned int* __restrict__ cnt,
                   unsigned int* __restrict__ ex0,
                   unsigned int* __restrict__ ex1,
                   const unsigned int* __restrict__ dec)
{
  __shared__ alignas(16) _Float16 sWi[NC * LDK];
  __shared__ alignas(16) _Float16 sWh[NC * LDK];
  __shared__ alignas(16) _Float16 sA [BC * LDK];
  __shared__ float sGi[BC * LDG];
  __shared__ float sGh[BC * LDG];
  __shared__ float sBh[NC];
  __shared__ int   sRst[BC];

  const int tid  = threadIdx.x;
  const int bid  = blockIdx.x;
  const int g    = bid & (NGROUP - 1);
  const int p    = bid >> 2;
  const int row0 = g * BC;
  const int col0 = p * HC;

  float* carryOut = out;
  float* ys = out + BATCH * HDIM;

  const unsigned int isBool = *dec;
  const unsigned char* r8  = (const unsigned char*)resets_raw;
  const int*           r32 = (const int*)resets_raw;

  unsigned int* ex[2] = { ex0, ex1 };
  unsigned int* myCnt = cnt + g * CNT_STRIDE;

  for (int idx = tid; idx < DIN * NC; idx += THREADS) {
    int k  = idx / NC;
    int ci = idx - k * NC;
    int gcol = (ci >> 4) * HDIM + col0 + (ci & 15);
    sWi[ci * LDK + k] = (_Float16)Wi[k * THREEH + gcol];
    sWh[ci * LDK + k] = (_Float16)Wh[k * THREEH + gcol];
  }
  if (tid < NC) {
    int gcol = (tid >> 4) * HDIM + col0 + (tid & 15);
    sBh[tid] = bh[gcol];
  }

  float hreg[2];
  {
    int idx = tid * 2;
    int b0 = idx >> 4, c0 = idx & 15;
    hreg[0] = carry[(size_t)(row0 + b0) * HDIM + col0 + c0];
    hreg[1] = carry[(size_t)(row0 + b0) * HDIM + col0 + c0 + 1];
  }

  const int wid  = tid >> 6;
  const int lane = tid & 63;

  auto stageRst = [&](int t) {
    if (tid < BC) {
      int off = t * BATCH + row0 + tid;
      sRst[tid] = isBool ? (int)r8[off] : r32[off];
    }
  };
  auto stageX = [&](int t) {
    const float4* src = (const float4*)(ins + (size_t)(t * BATCH + row0) * DIN);
    for (int i = tid; i < BC * (DIN / 4); i += THREADS) {
      int r = i >> 7, c4 = i & 127;
      float4 v = src[(size_t)r * 128 + c4];
      half4v hv = {(_Float16)v.x, (_Float16)v.y, (_Float16)v.z, (_Float16)v.w};
      *(half4v*)&sA[r * LDK + c4 * 4] = hv;
    }
  };

  stageRst(0);
  stageX(0);
  __syncthreads();
  run_gemm(sA, sWi, sGi, wid, lane);
  __syncthreads();
  {
    const float4* src = (const float4*)(carry + (size_t)row0 * HDIM);
    for (int i = tid; i < BC * (HDIM / 4); i += THREADS) {
      int r = i >> 7, c4 = i & 127;
      float4 v = src[(size_t)r * 128 + c4];
      float m = sRst[r] ? 0.f : 1.f;
      half4v hv = {(_Float16)(v.x*m), (_Float16)(v.y*m),
                   (_Float16)(v.z*m), (_Float16)(v.w*m)};
      *(half4v*)&sA[r * LDK + c4 * 4] = hv;
    }
  }
  __syncthreads();

  for (int t = 0; t < T_STEPS; ++t) {
    if (t > 0) {
      {
        const unsigned int target = 32u * (unsigned)t;
        unsigned int fv;
        for (int it = 0; it < SPIN_MAX; ++it) {
          asm volatile("global_load_dword %0, %1, off sc0 sc1\n\t"
                       "s_waitcnt vmcnt(0)"
                       : "=v"(fv) : "v"(myCnt) : "memory");
          if (fv >= target) break;
          __builtin_amdgcn_s_sleep(1);
        }
      }
      {
        const unsigned int* exsrc = ex[(t - 1) & 1];
        uint4v vv[8];
#pragma unroll
        for (int j = 0; j < 8; ++j) {
          int i = tid + THREADS * j;
          int p_ = i >> 6, b_ = (i >> 1) & 31, hw = (i & 1) << 2;
          const unsigned int* sp = exsrc + p_ * 1024 + (row0 + b_) * 8 + hw;
          asm volatile("global_load_dwordx4 %0, %1, off sc0 sc1"
                       : "=&v"(vv[j]) : "v"(sp) : "memory");
        }
        asm volatile("s_waitcnt vmcnt(0)" ::: "memory");
        __builtin_amdgcn_sched_barrier(0);
#pragma unroll
        for (int j = 0; j < 8; ++j) {
          int i = tid + THREADS * j;
          int p_ = i >> 6, b_ = (i >> 1) & 31, hw = (i & 1) << 3;
          half8 hv = *reinterpret_cast<half8*>(&vv[j]);
          half8 z = {(_Float16)0, (_Float16)0, (_Float16)0, (_Float16)0,
                     (_Float16)0, (_Float16)0, (_Float16)0, (_Float16)0};
          hv = sRst[b_] ? z : hv;
          *(half8*)&sA[b_ * LDK + p_ * 16 + hw] = hv;
        }
      }
      __syncthreads();
    }

    run_gemm(sA, sWh, sGh, wid, lane);
    __syncthreads();

    {
#pragma unroll
      for (int e = 0; e < 2; ++e) {
        int idx = tid * 2 + e;
        int b = idx >> 4, cj = idx & 15;
        float gir = sGi[b * LDG + cj];
        float giz = sGi[b * LDG + 16 + cj];
        float gin = sGi[b * LDG + 32 + cj];
        float ghr = sGh[b * LDG + cj]      + sBh[cj];
        float ghz = sGh[b * LDG + 16 + cj] + sBh[16 + cj];
        float ghn = sGh[b * LDG + 32 + cj] + sBh[32 + cj];
        float r = 1.f / (1.f + __expf(-(gir + ghr)));
        float z = 1.f / (1.f + __expf(-(giz + ghz)));
        float n = tanhf(gin + r * ghn);
        float hp = sRst[b] ? 0.f : hreg[e];
        hreg[e] = (1.f - z) * n + z * hp;
      }
      union { _Float16 h[2]; unsigned int u; } pk;
      pk.h[0] = (_Float16)hreg[0];
      pk.h[1] = (_Float16)hreg[1];
      unsigned int* dst = ex[t & 1] + p * 1024 + (row0 + (tid >> 3)) * 8 + (tid & 7);
      asm volatile("global_store_dword %0, %1, off sc0 sc1"
                   :: "v"(dst), "v"(pk.u) : "memory");
      int b0 = (tid * 2) >> 4, c0 = (tid * 2) & 15;
      float2 yv = make_float2(hreg[0], hreg[1]);
      *(float2*)&ys[((size_t)t * BATCH + row0 + b0) * HDIM + col0 + c0] = yv;
      if (t == T_STEPS - 1)
        *(float2*)&carryOut[(size_t)(row0 + b0) * HDIM + col0 + c0] = yv;
    }
    asm volatile("s_waitcnt vmcnt(0)" ::: "memory");
    __syncthreads();
    if (tid == 0) atomicAdd(myCnt, 1u);

    if (t < T_STEPS - 1) {
      stageRst(t + 1);
      stageX(t + 1);
      __syncthreads();
      run_gemm(sA, sWi, sGi, wid, lane);
      __syncthreads();
    }
  }
}

// ============ gi prepass v3: blocked output layout, coalesced stores ============
// gis[t][gamma][slice(32)][b(128)][c(16)] fp16: each C-tile lands contiguous.
__global__ __launch_bounds__(256, 1)
void gi_prepass3(const float* __restrict__ ins,
                 const float* __restrict__ Wi,
                 _Float16* __restrict__ gis)
{
  __shared__ alignas(16) _Float16 sWiT[48 * LDK];
  __shared__ alignas(16) _Float16 sX[32 * LDK];

  const int tid = threadIdx.x;
  const int bid = blockIdx.x;
  const int n   = bid >> 3;    // col-slice 0..31
  const int mg  = bid & 7;     // M-stripe of 8192 rows
  const int wid = tid >> 6;
  const int lane = tid & 63;
  const int fr = lane & 15;
  const int kb = (lane >> 4) * 8;

  for (int idx = tid; idx < 48 * DIN; idx += 256) {
    int ci = idx % 48, k = idx / 48;
    int gcol = (ci >> 4) * HDIM + n * 16 + (ci & 15);
    sWiT[ci * LDK + k] = (_Float16)Wi[(size_t)k * THREEH + gcol];
  }

  float4 va[16];
  auto LOADS = [&](int ch) {
    const float4* src = (const float4*)(ins + (size_t)(mg * 8192 + ch * 32) * DIN);
#pragma unroll
    for (int j = 0; j < 16; ++j) va[j] = src[tid + 256 * j];
  };
  auto WRITE = [&]() {
#pragma unroll
    for (int j = 0; j < 16; ++j) {
      int i = tid + 256 * j;
      int r = i >> 7, c4 = i & 127;
      float4 v = va[j];
      half4v hv = {(_Float16)v.x, (_Float16)v.y, (_Float16)v.z, (_Float16)v.w};
      *(half4v*)&sX[r * LDK + c4 * 4] = hv;
    }
  };

  LOADS(0);
  for (int ch = 0; ch < 256; ++ch) {
    WRITE();
    __syncthreads();
    if (ch + 1 < 256) LOADS(ch + 1);

    const int m0 = mg * 8192 + ch * 32;
    const int tt = m0 >> 7;            // step (32-row chunk never crosses t)
    const int bb0 = m0 & 127;
    for (int tile = wid; tile < 6; tile += 4) {
      int mi = tile / 3, ni = tile - mi * 3;
      const _Float16* ap = sX   + (mi * 16 + fr) * LDK + kb;
      const _Float16* bp = sWiT + (ni * 16 + fr) * LDK + kb;
      f32x4 acc = {0.f, 0.f, 0.f, 0.f};
#pragma unroll
      for (int kk = 0; kk < DIN / 32; ++kk)
        acc = __builtin_amdgcn_mfma_f32_16x16x32_f16(
            *(const half8*)(ap + kk * 32),
            *(const half8*)(bp + kk * 32), acc, 0, 0, 0);
      int gr = mi * 16 + ((lane >> 4) << 2);
      size_t cbase = (((size_t)(tt * 3 + ni) * 32 + n) * 128) * 16;
#pragma unroll
      for (int j = 0; j < 4; ++j)
        gis[cbase + (size_t)(bb0 + gr + j) * 16 + fr] = (_Float16)acc[j];
    }
    __syncthreads();
  }
}

// ============ v9: round-8 v4 body + nonce handshake + epoch'd flags ============
__device__ __forceinline__ void gridbar9(unsigned int* ctr, int tid) {
  __syncthreads();
  if (tid == 0) {
    atomicAdd(ctr, 1u);
    unsigned int v;
    for (int it = 0; it < SPIN_MAX; ++it) {
      asm volatile("global_load_dword %0, %1, off sc0 sc1\n\t"
                   "s_waitcnt vmcnt(0)" : "=v"(v) : "v"(ctr) : "memory");
      if (v >= 256u) break;
      __builtin_amdgcn_s_sleep(1);
    }
  }
  __syncthreads();
}

__global__ __launch_bounds__(THREADS, 1)
void gru_kernel_v9(const float* __restrict__ carry,
                   const void*  __restrict__ resets_raw,
                   const float* __restrict__ Wh,
                   const float* __restrict__ bh,
                   float* __restrict__ out,
                   unsigned int* __restrict__ wsb,
                   const _Float16* __restrict__ gis,
                   const unsigned int* __restrict__ dec)
{
  __shared__ alignas(16) _Float16 sWh[NC * LDK];   // ~50KB
  __shared__ alignas(16) _Float16 sA [RW * LDK];   // ~16.6KB
  __shared__ float sGh[RW * LDG];
  __shared__ float sBh[NC];
  __shared__ int   sRst[RW];
  __shared__ int   sFast;
  __shared__ unsigned int sNonce;

  const int tid  = threadIdx.x;
  const int bid  = blockIdx.x;
  const int g    = bid & 7;        // cohort (presumed XCD)
  const int p    = bid >> 3;       // col slice 0..31
  const int row0 = g * RW;
  const int col0 = p * HC;

  unsigned int* flags    = wsb + (FLAGS_OFF / 4);   // [g*32+p]
  unsigned int* gbars    = wsb + (GBAR_OFF / 4);
  unsigned int* nonceArr = wsb + (NONCE_OFF / 4);
  unsigned int* vd       = wsb + (VD_OFF / 4);
  unsigned int* hs       = wsb + (HS_OFF / 4);
  char*         exb      = (char*)wsb + EX_OFF;

  float* carryOut = out;
  float* ys = out + BATCH * HDIM;

  const unsigned int isBool = *dec;
  const unsigned char* r8  = (const unsigned char*)resets_raw;
  const int*           r32 = (const int*)resets_raw;
  const unsigned short* gisu = (const unsigned short*)gis;

  const int wid  = tid >> 6;
  const int lane = tid & 63;
  const int fr   = lane & 15;
  const int kb   = (lane >> 4) * 8;
  const int gb   = tid >> 4;       // batch row 0..15
  const int gc   = tid & 15;       // col 0..15

  // ---- weights / bias ----
  for (int idx = tid; idx < DIN * NC; idx += THREADS) {
    int k  = idx / NC;
    int ci = idx - k * NC;
    int gcol = (ci >> 4) * HDIM + col0 + (ci & 15);
    sWh[ci * LDK + k] = (_Float16)Wh[(size_t)k * THREEH + gcol];
  }
  if (tid < NC) {
    int gcol = (tid >> 4) * HDIM + col0 + (tid & 15);
    sBh[tid] = bh[gcol];
  }
  float hreg = carry[(size_t)(row0 + gb) * HDIM + col0 + gc];

  // ---- nonce handshake (poll-until-match, proven) ----
  if (p == 0 && tid == 0) {
    unsigned long long tv = __builtin_amdgcn_s_memrealtime();
    unsigned int nv = (unsigned int)(tv ^ (tv >> 32));
    if (nv == 0) nv = 0x5A5A5A5Au;
    asm volatile("global_store_dword %0, %1, off sc0 sc1\n\t"
                 "s_waitcnt vmcnt(0)" :: "v"(nonceArr + g), "v"(nv) : "memory");
  }
  gridbar9(gbars + 0 * 16, tid);
  if (tid == 0) {
    unsigned int nv;
    asm volatile("global_load_dword %0, %1, off sc0 sc1\n\t"
                 "s_waitcnt vmcnt(0)" : "=v"(nv) : "v"(nonceArr + g) : "memory");
    sNonce = nv;
  }
  __syncthreads();
  const unsigned int nonce = sNonce;
  unsigned int ep16 = (nonce >> 16) ^ (nonce & 0xFFFFu);
  if (ep16 == 0) ep16 = 0xA5A5u;      // epoch tag, never 0

  bool okAll = true;
  for (int r = 0; r < 2; ++r) {
    if (tid == 0) {
      unsigned int tok = nonce ^ ((unsigned)p << 8) ^ ((unsigned)(r + 1) << 20);
      asm volatile("global_store_dword %0, %1, off sc0\n\t"
                   "s_waitcnt vmcnt(0)" :: "v"(hs + bid), "v"(tok) : "memory");
    }
    __syncthreads();
    if (tid < 32) {
      unsigned int expv = nonce ^ ((unsigned)tid << 8) ^ ((unsigned)(r + 1) << 20);
      const unsigned int* hp = hs + (g + 8 * tid);
      bool got = false;
      for (int it = 0; it < HS_SPIN && !got; ++it) {
        unsigned int v;
        asm volatile("global_load_dword %0, %1, off sc0\n\t"
                     "s_waitcnt vmcnt(0)" : "=v"(v) : "v"(hp) : "memory");
        got = (v == expv);
      }
      okAll = okAll && got;
    }
    gridbar9(gbars + (1 + r) * 16, tid);
  }
  {
    bool wgok = __all((tid < 32) ? okAll : true);
    if (tid == 0) {
      unsigned int vv = wgok ? 1u : 0u;
      asm volatile("global_store_dword %0, %1, off sc0 sc1\n\t"
                   "s_waitcnt vmcnt(0)" :: "v"(vd + bid), "v"(vv) : "memory");
    }
    gridbar9(gbars + 3 * 16, tid);
    bool fin = true;
    if (tid < 32) {
      unsigned int v;
      asm volatile("global_load_dword %0, %1, off sc0 sc1\n\t"
                   "s_waitcnt vmcnt(0)" : "=v"(v) : "v"(vd + (g + 8 * tid)) : "memory");
      fin = (v == 1u);
    }
    bool unan = __all((tid < 32) ? fin : true);
    if (tid == 0) sFast = unan ? 1 : 0;
    __syncthreads();
  }
  const int fast = sFast;

  // ---- prologue: rst(0) + masked-carry stage into sA ----
  if (tid < RW) {
    int off = row0 + tid;
    sRst[tid] = isBool ? (int)r8[off] : r32[off];
  }
  __syncthreads();
  {
    const float4* src = (const float4*)(carry + (size_t)row0 * HDIM);
    for (int i = tid; i < RW * 128; i += THREADS) {
      int r = i >> 7, c4 = i & 127;
      float4 v = src[(size_t)r * 128 + c4];
      float m = sRst[r] ? 0.f : 1.f;
      half4v hv = {(_Float16)(v.x*m), (_Float16)(v.y*m),
                   (_Float16)(v.z*m), (_Float16)(v.w*m)};
      *(half4v*)&sA[r * LDK + c4 * 4] = hv;
    }
  }

  for (int t = 0; t < T_STEPS; ++t) {
    const int slot = t & 1;
    // gi loads (blocked layout; recurrence-independent, drained with the wait)
    unsigned short gu0, gu1, gu2;
    {
      size_t gbase = (((size_t)(t * 3) * 32 + p) * 128 + row0 + gb) * 16 + gc;
      gu0 = gisu[gbase];
      gu1 = gisu[gbase + GI_GSTRIDE];
      gu2 = gisu[gbase + 2 * GI_GSTRIDE];
    }
    if (t > 0 && tid < RW) {
      int off = t * BATCH + row0 + tid;
      sRst[tid] = isBool ? (int)r8[off] : r32[off];
    }
    // wait: epoch'd flags, 32 lanes poll one 128B line
    if (t > 0) {
      bool done = false;
      const unsigned int* fp = flags + (g * 32 + (tid & 31));
      for (int it = 0; it < SPIN_MAX && !done; ++it) {
        unsigned int fv = 0xFFFFFFFFu;
        bool ok = true;
        if (tid < 32) {
          if (fast) {
            asm volatile("global_load_dword %0, %1, off sc0\n\t"
                         "s_waitcnt vmcnt(0)" : "=v"(fv) : "v"(fp) : "memory");
          } else {
            asm volatile("global_load_dword %0, %1, off sc0 sc1\n\t"
                         "s_waitcnt vmcnt(0)" : "=v"(fv) : "v"(fp) : "memory");
          }
          ok = ((fv >> 16) == ep16) && ((fv & 0xFFFFu) >= (unsigned)t);
        }
        done = __all(ok);
        if (!done) __builtin_amdgcn_s_sleep(1);
      }
    }
    __syncthreads();

    if (t > 0) {
      // stage h_{t-1}: 16KB from cohort-local exchange
      const char* src = exb + (slot ^ 1) * EXSLOT + g * 16384
                      + (tid >> 4) * 1024 + (tid & 15) * 64;
      uint4v v0, v1, v2, v3;
      if (fast) {
        asm volatile("global_load_dwordx4 %0, %4, off sc0\n\t"
                     "global_load_dwordx4 %1, %4, off offset:16 sc0\n\t"
                     "global_load_dwordx4 %2, %4, off offset:32 sc0\n\t"
                     "global_load_dwordx4 %3, %4, off offset:48 sc0\n\t"
                     "s_waitcnt vmcnt(0)"
                     : "=&v"(v0), "=&v"(v1), "=&v"(v2), "=&v"(v3)
                     : "v"(src) : "memory");
      } else {
        asm volatile("global_load_dwordx4 %0, %4, off sc0 sc1\n\t"
                     "global_load_dwordx4 %1, %4, off offset:16 sc0 sc1\n\t"
                     "global_load_dwordx4 %2, %4, off offset:32 sc0 sc1\n\t"
                     "global_load_dwordx4 %3, %4, off offset:48 sc0 sc1\n\t"
                     "s_waitcnt vmcnt(0)"
                     : "=&v"(v0), "=&v"(v1), "=&v"(v2), "=&v"(v3)
                     : "v"(src) : "memory");
      }
      __builtin_amdgcn_sched_barrier(0);
      int r = tid >> 4, c0 = (tid & 15) * 32;
      half8 h0 = *reinterpret_cast<half8*>(&v0);
      half8 h1 = *reinterpret_cast<half8*>(&v1);
      half8 h2 = *reinterpret_cast<half8*>(&v2);
      half8 h3 = *reinterpret_cast<half8*>(&v3);
      half8 z = {(_Float16)0, (_Float16)0, (_Float16)0, (_Float16)0,
                 (_Float16)0, (_Float16)0, (_Float16)0, (_Float16)0};
      if (sRst[r]) { h0 = z; h1 = z; h2 = z; h3 = z; }
      *(half8*)&sA[r * LDK + c0 +  0] = h0;
      *(half8*)&sA[r * LDK + c0 +  8] = h1;
      *(half8*)&sA[r * LDK + c0 + 16] = h2;
      *(half8*)&sA[r * LDK + c0 + 24] = h3;
      __syncthreads();
    }

    // gh GEMM: M=16, 3 N-tiles over waves 0..2 (split-K pair)
    if (wid < 3) {
      const _Float16* ap = sA  + fr * LDK + kb;
      const _Float16* bp = sWh + (wid * 16 + fr) * LDK + kb;
      f32x4 a0 = {0.f, 0.f, 0.f, 0.f}, a1 = {0.f, 0.f, 0.f, 0.f};
#pragma unroll
      for (int kk = 0; kk < DIN / 32; kk += 2) {
        a0 = __builtin_amdgcn_mfma_f32_16x16x32_f16(
            *(const half8*)(ap + kk * 32), *(const half8*)(bp + kk * 32), a0, 0, 0, 0);
        a1 = __builtin_amdgcn_mfma_f32_16x16x32_f16(
            *(const half8*)(ap + (kk + 1) * 32), *(const half8*)(bp + (kk + 1) * 32), a1, 0, 0, 0);
      }
      a0 += a1;
      int crow = (lane >> 4) * 4;
      int ccol = wid * 16 + fr;
#pragma unroll
      for (int j = 0; j < 4; ++j) sGh[(crow + j) * LDG + ccol] = a0[j];
    }
    __syncthreads();

    // gates (1 elem/thread) + publish
    {
      union { unsigned short u; _Float16 h; } c0_, c1_, c2_;
      c0_.u = gu0; c1_.u = gu1; c2_.u = gu2;
      float gir = (float)c0_.h;
      float giz = (float)c1_.h;
      float gin = (float)c2_.h;
      float ghr = sGh[gb * LDG + gc]      + sBh[gc];
      float ghz = sGh[gb * LDG + 16 + gc] + sBh[16 + gc];
      float ghn = sGh[gb * LDG + 32 + gc] + sBh[32 + gc];
      float r = 1.f / (1.f + __expf(-(gir + ghr)));
      float z = 1.f / (1.f + __expf(-(giz + ghz)));
      float n = tanhf(gin + r * ghn);
      float hp = sRst[gb] ? 0.f : hreg;
      hreg = (1.f - z) * n + z * hp;

      if (t < T_STEPS - 1) {
        union { _Float16 h; unsigned short u; } pk;
        pk.h = (_Float16)hreg;
        unsigned int pv = (unsigned int)pk.u;
        unsigned short* dst = (unsigned short*)
          (exb + slot * EXSLOT + g * 16384 + gb * 1024 + (col0 + gc) * 2);
        if (fast) {
          asm volatile("global_store_short %0, %1, off sc0"
                       :: "v"(dst), "v"(pv) : "memory");
        } else {
          asm volatile("global_store_short %0, %1, off sc0 sc1"
                       :: "v"(dst), "v"(pv) : "memory");
        }
      }
    }
    asm volatile("s_waitcnt vmcnt(0)" ::: "memory");   // publish drained
    __syncthreads();                                   // all waves drained
    if (tid == 0 && t < T_STEPS - 1) {
      unsigned int* fp = flags + (g * 32 + p);
      unsigned int val = (ep16 << 16) | (unsigned)(t + 1);
      if (fast) {
        asm volatile("global_store_dword %0, %1, off sc0"
                     :: "v"(fp), "v"(val) : "memory");
      } else {
        asm volatile("global_store_dword %0, %1, off sc0 sc1"
                     :: "v"(fp), "v"(val) : "memory");
      }
    }
    // ys (write-only) after the flag, off the critical path
    {
      ys[((size_t)t * BATCH + row0 + gb) * HDIM + col0 + gc] = hreg;
      if (t == T_STEPS - 1)
        carryOut[(size_t)(row0 + gb) * HDIM + col0 + gc] = hreg;
    }
  }

  // flush dirty L2 lines so no stale data leaks into a later replay
  __builtin_amdgcn_fence(__ATOMIC_RELEASE, "agent");
}

extern "C" void kernel_launch(void* const* d_in, const int* in_sizes, int n_in,
                              void* d_out, int out_size, void* d_ws, size_t ws_size,
                              hipStream_t stream) {
  const float* carry  = (const float*)d_in[0];
  const float* ins    = (const float*)d_in[1];
  const void*  resets = (const void*)d_in[2];
  const float* Wi     = (const float*)d_in[3];
  const float* Wh     = (const float*)d_in[4];
  const float* bh     = (const float*)d_in[5];
  float* out = (float*)d_out;

  unsigned int* wsb  = (unsigned int*)d_ws;
  unsigned int* dec  = (unsigned int*)((char*)d_ws + DEC_OFF);
  unsigned int* ex0  = (unsigned int*)((char*)d_ws + EX_OFF);
  unsigned int* ex1  = ex0 + EX_DWORDS;
  _Float16*     gis  = (_Float16*)((char*)d_ws + GI_OFF);

  (void)hipMemsetAsync(d_ws, 0, MEMSET_BYTES, stream);

  sniff_kernel<<<dim3(1), dim3(256), 0, stream>>>(
      (const unsigned int*)resets, dec);

  const bool bigWs = ws_size >= (size_t)GI_OFF + GI_BYTES;

  if (bigWs) {
    gi_prepass3<<<dim3(256), dim3(256), 0, stream>>>(ins, Wi, gis);
    void* args[] = { (void*)&carry, (void*)&resets, (void*)&Wh, (void*)&bh,
                     (void*)&out, (void*)&wsb, (void*)&gis, (void*)&dec };
    (void)hipLaunchCooperativeKernel((const void*)gru_kernel_v9,
                                     dim3(256), dim3(THREADS),
                                     args, 0, stream);
  } else {
    void* args[] = { (void*)&carry, (void*)&ins, (void*)&resets, (void*)&Wi,
                     (void*)&Wh, (void*)&bh, (void*)&out, (void*)&wsb,
                     (void*)&ex0, (void*)&ex1, (void*)&dec };
    (void)hipLaunchCooperativeKernel((const void*)gru_kernel_v1,
                                     dim3(NGROUP * NSLICE), dim3(THREADS),
                                     args, 0, stream);
  }
}